// Round 4
// baseline (433.541 us; speedup 1.0000x reference)
//
#include <hip/hip_runtime.h>

#define N_  4096
#define D_  64
#define C_  256
#define NT  256

typedef short bf16x8 __attribute__((ext_vector_type(8)));
typedef float f32x4  __attribute__((ext_vector_type(4)));

__device__ __forceinline__ unsigned short f2bf(float f) {
    union { float f; unsigned int i; } v; v.f = f;
    unsigned int r = v.i + 0x7fffu + ((v.i >> 16) & 1u);
    return (unsigned short)(r >> 16);
}

// ---------- fused prepass: cvt q, cvt pg, transpose v ----------
// blocks [0,256): q->bf16 ; [256,512): pg->bf16 ; [512,1536): v -> vt[b][c][j] bf16
__global__ void prepass_kernel(const float* __restrict__ xq,
                               const float* __restrict__ pg,
                               const float* __restrict__ xv,
                               unsigned short* __restrict__ qbf,
                               unsigned short* __restrict__ pgbf,
                               unsigned short* __restrict__ vt) {
    const int bid = blockIdx.x;
    const int t   = threadIdx.x;
    if (bid < 512) {
        const float* src = (bid < 256) ? xq : pg;
        unsigned short* dst = (bid < 256) ? qbf : pgbf;
        const int base = (bid & 255) * 1024;   // float4 index
#pragma unroll
        for (int it = 0; it < 4; ++it) {
            const int i = base + it * 256 + t;
            float4 v = ((const float4*)src)[i];
            ushort4 o;
            o.x = f2bf(v.x); o.y = f2bf(v.y); o.z = f2bf(v.z); o.w = f2bf(v.w);
            ((ushort4*)dst)[i] = o;
        }
        return;
    }
    __shared__ float s[64][65];
    const int tb = bid - 512;
    const int b  = tb >> 8;
    const int jt = tb & 63;
    const int ct = (tb >> 6) & 3;
    const int j0 = jt * 64, c0 = ct * 64;
#pragma unroll
    for (int it = 0; it < 16; ++it) {
        const int jl = it * 4 + (t >> 6);
        const int cl = t & 63;
        s[jl][cl] = xv[((size_t)b * N_ + j0 + jl) * C_ + c0 + cl];
    }
    __syncthreads();
#pragma unroll
    for (int it = 0; it < 16; ++it) {
        const int cl = it * 4 + (t >> 6);
        const int jl = t & 63;
        vt[((size_t)b * C_ + c0 + cl) * N_ + j0 + jl] = f2bf(s[jl][cl]);
    }
}

// ---------- main: barrier-free MFMA attention ----------
// 512 blocks, 4 waves. Block = 32 rows (2 m-groups of 16) x full j.
// Wave (mg, jh): rows [m0, m0+16), j in half jh. No barriers in the K-loop:
// P round-trips through a PRIVATE per-wave LDS tile (intra-wave lgkmcnt only).
__global__ __launch_bounds__(NT, 2) void attn_main(
    const float* __restrict__ g,  const float* __restrict__ x,
    const float* __restrict__ kk, float* __restrict__ out,
    const unsigned short* __restrict__ qbf,
    const unsigned short* __restrict__ pgbf,
    const unsigned short* __restrict__ vt)
{
    __shared__ __align__(16) unsigned short p_lds[4][16][40]; // stride 80B: 16B-aligned, <=2-way conflicts
    __shared__ __align__(16) float s_red[2][16][260];         // padded: +4 banks/row
    __shared__ float s_l[4][16];

    const int t    = threadIdx.x;
    const int lane = t & 63;
    const int w    = t >> 6;
    const int l15  = lane & 15;
    const int quad = lane >> 4;

    // XCD-swizzled block decode: batch b pinned to XCDs {2b, 2b+1}
    const int bid = blockIdx.x;
    const int b   = (bid & 7) >> 1;
    const int ig  = (bid >> 3) * 2 + (bid & 1);   // 0..127
    const int i0  = ig * 32;
    const int mg  = w >> 1;
    const int jh  = w & 1;
    const int m0  = i0 + mg * 16;
    const size_t rowbase  = (size_t)b * N_ + i0;
    const size_t mrowbase = (size_t)b * N_ + m0;

    // ---- g passthrough: out[.., 256:512] = g (32 rows) ----
#pragma unroll
    for (int it = 0; it < 8; ++it) {
        const int row = it * 4 + w;
        const int c4  = lane * 4;
        const float4 gv = *(const float4*)(g + (rowbase + row) * C_ + c4);
        *(float4*)(out + (rowbase + row) * (2 * C_) + C_ + c4) = gv;
    }

    // ---- pg B-frags for this wave's 16 rows (reused all chunks) ----
    bf16x8 pgf[2];
#pragma unroll
    for (int ks = 0; ks < 2; ++ks)
        pgf[ks] = *(const bf16x8*)(pgbf + (mrowbase + l15) * D_ + ks * 32 + quad * 8);

    f32x4 oacc[16];
#pragma unroll
    for (int ct = 0; ct < 16; ++ct) oacc[ct] = (f32x4){0.f, 0.f, 0.f, 0.f};
    float ls[4] = {0.f, 0.f, 0.f, 0.f};

    const unsigned short* qb  = qbf + (size_t)b * N_ * D_;
    const unsigned short* vtb = vt  + (size_t)b * C_ * N_;

    // ---- K-loop: 64 chunks of 32 j, NO barriers ----
    for (int jc = 0; jc < 64; ++jc) {
        const int j0 = jh * 2048 + jc * 32;

        // S = pg . q^T : two 16x16 tiles (C-layout: lane holds S[m=quad*4+r][j=l15])
#pragma unroll
        for (int js = 0; js < 2; ++js) {
            f32x4 sacc = (f32x4){0.f, 0.f, 0.f, 0.f};
#pragma unroll
            for (int ks = 0; ks < 2; ++ks) {
                const bf16x8 qf = *(const bf16x8*)(qb +
                    (size_t)(j0 + js * 16 + l15) * D_ + ks * 32 + quad * 8);
                sacc = __builtin_amdgcn_mfma_f32_16x16x32_bf16(pgf[ks], qf, sacc, 0, 0, 0);
            }
#pragma unroll
            for (int r = 0; r < 4; ++r) {
                const float p = __expf(sacc[r]);   // |s| small: no max-sub needed
                ls[r] += p;
                p_lds[w][quad * 4 + r][js * 16 + l15] = f2bf(p);
            }
        }

        // intra-wave LDS round-trip: wait our own ds_writes, no __syncthreads
        asm volatile("s_waitcnt lgkmcnt(0)" ::: "memory");
        const bf16x8 pa = *(const bf16x8*)&p_lds[w][l15][quad * 8];

        // O += P . V  (B-frags: V^T rows, 16B contiguous)
#pragma unroll
        for (int ct = 0; ct < 16; ++ct) {
            const bf16x8 vf = *(const bf16x8*)(vtb +
                (size_t)(ct * 16 + l15) * N_ + j0 + quad * 8);
            oacc[ct] = __builtin_amdgcn_mfma_f32_16x16x32_bf16(pa, vf, oacc[ct], 0, 0, 0);
        }
    }

    // ---- row-sum reduce over the 16 j-lanes ----
#pragma unroll
    for (int r = 0; r < 4; ++r) {
        float s = ls[r];
        s += __shfl_xor(s, 1); s += __shfl_xor(s, 2);
        s += __shfl_xor(s, 4); s += __shfl_xor(s, 8);
        ls[r] = s;
    }
    if (l15 == 0) {
#pragma unroll
        for (int r = 0; r < 4; ++r) s_l[w][quad * 4 + r] = ls[r];
    }

    // ---- O reduction across j-halves ----
    if (jh == 1) {
#pragma unroll
        for (int ct = 0; ct < 16; ++ct)
#pragma unroll
            for (int r = 0; r < 4; ++r)
                s_red[mg][quad * 4 + r][ct * 16 + l15] = oacc[ct][r];
    }
    __syncthreads();

    if (jh == 0) {
        const float kval = kk[0];
        float linv[4];
#pragma unroll
        for (int r = 0; r < 4; ++r)
            linv[r] = 1.f / (s_l[mg * 2][quad * 4 + r] + s_l[mg * 2 + 1][quad * 4 + r]);
#pragma unroll
        for (int ct = 0; ct < 16; ++ct)
#pragma unroll
            for (int r = 0; r < 4; ++r) {
                const int m = quad * 4 + r;
                const int c = ct * 16 + l15;
                const float o = oacc[ct][r] + s_red[mg][m][c];
                out[(mrowbase + m) * (2 * C_) + c] =
                    kval * (o * linv[r]) + x[(mrowbase + m) * C_ + c];
            }
    }
}

// ---------- fallback (round-2 vector kernel) if workspace too small ----------
#define ROWS 4
__global__ __launch_bounds__(NT, 2) void attn_fallback(
    const float* __restrict__ g, const float* __restrict__ x,
    const float* __restrict__ xq, const float* __restrict__ pg,
    const float* __restrict__ xv, const float* __restrict__ kk,
    float* __restrict__ out)
{
    __shared__ __align__(16) float s_pg[ROWS][D_];
    __shared__ __align__(16) float s_sc[N_ * ROWS];
    __shared__ float s_rmax[4][ROWS];
    __shared__ float s_rsum[4][ROWS];

    const int t = threadIdx.x, lane = t & 63, w = t >> 6, blk = blockIdx.x;
    const int b = blk >> 10, i0 = (blk & 1023) * ROWS;
    const size_t rowbase = (size_t)b * N_ + i0;
    {
        const int r = t >> 6, cc = (t & 63) * 4;
        const float4 gv = *(const float4*)(g + (rowbase + r) * C_ + cc);
        *(float4*)(out + (rowbase + r) * (2 * C_) + C_ + cc) = gv;
    }
    { const int r = t >> 6, d = t & 63; s_pg[r][d] = pg[(rowbase + r) * D_ + d]; }
    __syncthreads();
    const float* qb = xq + (size_t)b * N_ * D_;
    float lmax[ROWS];
#pragma unroll
    for (int r = 0; r < ROWS; ++r) lmax[r] = -1e30f;
    for (int jj = 0; jj < N_ / NT; ++jj) {
        const int j = t + jj * NT;
        const float4* q4p = (const float4*)(qb + (size_t)j * D_);
        float s[ROWS] = {0.f, 0.f, 0.f, 0.f};
#pragma unroll
        for (int u = 0; u < D_ / 8; ++u) {
            const float4 qa = q4p[u * 2], qc = q4p[u * 2 + 1];
#pragma unroll
            for (int r = 0; r < ROWS; ++r) {
                const float4 pa = *(const float4*)&s_pg[r][u * 8];
                const float4 pb = *(const float4*)&s_pg[r][u * 8 + 4];
                s[r] += qa.x * pa.x + qa.y * pa.y + qa.z * pa.z + qa.w * pa.w
                      + qc.x * pb.x + qc.y * pb.y + qc.z * pb.z + qc.w * pb.w;
            }
        }
        *(float4*)&s_sc[j * ROWS] = make_float4(s[0], s[1], s[2], s[3]);
#pragma unroll
        for (int r = 0; r < ROWS; ++r) lmax[r] = fmaxf(lmax[r], s[r]);
    }
#pragma unroll
    for (int r = 0; r < ROWS; ++r) {
        float m = lmax[r];
        for (int o = 32; o > 0; o >>= 1) m = fmaxf(m, __shfl_down(m, o));
        if (lane == 0) s_rmax[w][r] = m;
    }
    __syncthreads();
    float bmax[ROWS];
#pragma unroll
    for (int r = 0; r < ROWS; ++r)
        bmax[r] = fmaxf(fmaxf(s_rmax[0][r], s_rmax[1][r]), fmaxf(s_rmax[2][r], s_rmax[3][r]));
    float lsum[ROWS] = {0.f, 0.f, 0.f, 0.f};
    for (int jj = 0; jj < N_ / NT; ++jj) {
        const int j = t + jj * NT;
        float4 s4 = *(const float4*)&s_sc[j * ROWS];
        s4.x = __expf(s4.x - bmax[0]); s4.y = __expf(s4.y - bmax[1]);
        s4.z = __expf(s4.z - bmax[2]); s4.w = __expf(s4.w - bmax[3]);
        *(float4*)&s_sc[j * ROWS] = s4;
        lsum[0] += s4.x; lsum[1] += s4.y; lsum[2] += s4.z; lsum[3] += s4.w;
    }
#pragma unroll
    for (int r = 0; r < ROWS; ++r) {
        float sm = lsum[r];
        for (int o = 32; o > 0; o >>= 1) sm += __shfl_down(sm, o);
        if (lane == 0) s_rsum[w][r] = sm;
    }
    __syncthreads();
    float rinv[ROWS];
#pragma unroll
    for (int r = 0; r < ROWS; ++r)
        rinv[r] = 1.f / (s_rsum[0][r] + s_rsum[1][r] + s_rsum[2][r] + s_rsum[3][r]);
    const int jg = lane >> 4;
    const int c0 = (w * 16 + (lane & 15)) * 4;
    const float* vb = xv + (size_t)b * N_ * C_;
    float acc[ROWS][4];
#pragma unroll
    for (int r = 0; r < ROWS; ++r)
#pragma unroll
        for (int q = 0; q < 4; ++q) acc[r][q] = 0.f;
#pragma unroll 4
    for (int jj = 0; jj < N_ / 4; ++jj) {
        const int j = jj * 4 + jg;
        const float4 p4 = *(const float4*)&s_sc[j * ROWS];
        const float4 v4 = *(const float4*)(vb + (size_t)j * C_ + c0);
        acc[0][0] += p4.x * v4.x; acc[0][1] += p4.x * v4.y; acc[0][2] += p4.x * v4.z; acc[0][3] += p4.x * v4.w;
        acc[1][0] += p4.y * v4.x; acc[1][1] += p4.y * v4.y; acc[1][2] += p4.y * v4.z; acc[1][3] += p4.y * v4.w;
        acc[2][0] += p4.z * v4.x; acc[2][1] += p4.z * v4.y; acc[2][2] += p4.z * v4.z; acc[2][3] += p4.z * v4.w;
        acc[3][0] += p4.w * v4.x; acc[3][1] += p4.w * v4.y; acc[3][2] += p4.w * v4.z; acc[3][3] += p4.w * v4.w;
    }
#pragma unroll
    for (int r = 0; r < ROWS; ++r)
#pragma unroll
        for (int q = 0; q < 4; ++q) {
            acc[r][q] += __shfl_xor(acc[r][q], 16);
            acc[r][q] += __shfl_xor(acc[r][q], 32);
        }
    const float kval = kk[0];
    if (lane < 16) {
        const int c = (w * 16 + lane) * 4;
#pragma unroll
        for (int r = 0; r < ROWS; ++r) {
            const float4 xv4 = *(const float4*)(x + (rowbase + r) * C_ + c);
            float4 ov;
            ov.x = kval * (acc[r][0] * rinv[r]) + xv4.x;
            ov.y = kval * (acc[r][1] * rinv[r]) + xv4.y;
            ov.z = kval * (acc[r][2] * rinv[r]) + xv4.z;
            ov.w = kval * (acc[r][3] * rinv[r]) + xv4.w;
            *(float4*)(out + (rowbase + r) * (2 * C_) + c) = ov;
        }
    }
}

extern "C" void kernel_launch(void* const* d_in, const int* in_sizes, int n_in,
                              void* d_out, int out_size, void* d_ws, size_t ws_size,
                              hipStream_t stream) {
    const float* g  = (const float*)d_in[0];
    const float* x  = (const float*)d_in[1];
    const float* xq = (const float*)d_in[2];
    const float* pg = (const float*)d_in[3];
    const float* xv = (const float*)d_in[4];
    const float* kk = (const float*)d_in[5];
    float* out = (float*)d_out;

    const int B = in_sizes[0] / (N_ * C_);   // 4
    const size_t qn = (size_t)B * N_ * D_;
    const size_t vn = (size_t)B * N_ * C_;
    const size_t need = (2 * qn + vn) * sizeof(unsigned short);

    if (ws_size < need) {
        attn_fallback<<<dim3(B * (N_ / ROWS)), NT, 0, stream>>>(g, x, xq, pg, xv, kk, out);
        return;
    }

    unsigned short* qbf  = (unsigned short*)d_ws;
    unsigned short* pgbf = qbf + qn;
    unsigned short* vtw  = pgbf + qn;

    prepass_kernel<<<dim3(512 + B * 256), NT, 0, stream>>>(xq, pg, xv, qbf, pgbf, vtw);
    attn_main<<<dim3(B * (N_ / 32)), NT, 0, stream>>>(g, x, kk, out, qbf, pgbf, vtw);
}

// Round 5
// 252.075 us; speedup vs baseline: 1.7199x; 1.7199x over previous
//
#include <hip/hip_runtime.h>

#define N_  4096
#define D_  64
#define C_  256

typedef short bf16x8 __attribute__((ext_vector_type(8)));
typedef float f32x4  __attribute__((ext_vector_type(4)));

union frag_u { bf16x8 f; unsigned int u[4]; uint2 u2[2]; };

__device__ __forceinline__ unsigned short f2bf(float f) {
    union { float f; unsigned int i; } v; v.f = f;
    unsigned int r = v.i + 0x7fffu + ((v.i >> 16) & 1u);
    return (unsigned short)(r >> 16);
}

// ---------- fused prepass ----------
// blocks [0,256): q->bf16 ; [256,512): pg->bf16 ; [512,1536): v -> vt[b][c][j] bf16
__global__ void prepass_kernel(const float* __restrict__ xq,
                               const float* __restrict__ pg,
                               const float* __restrict__ xv,
                               unsigned short* __restrict__ qbf,
                               unsigned short* __restrict__ pgbf,
                               unsigned short* __restrict__ vt) {
    __shared__ float s[64][65];
    const int bid = blockIdx.x;
    const int t   = threadIdx.x;
    if (bid < 512) {
        const float* src = (bid < 256) ? xq : pg;
        unsigned short* dst = (bid < 256) ? qbf : pgbf;
        const int base = (bid & 255) * 1024 + t;
#pragma unroll
        for (int it = 0; it < 4; ++it) {
            const int i = base + it * 256;
            float4 v = ((const float4*)src)[i];
            ushort4 o;
            o.x = f2bf(v.x); o.y = f2bf(v.y); o.z = f2bf(v.z); o.w = f2bf(v.w);
            ((ushort4*)dst)[i] = o;
        }
        return;
    }
    const int tb = bid - 512;
    const int b  = tb >> 8;
    const int jt = tb & 63;
    const int ct = (tb >> 6) & 3;
    const int j0 = jt * 64, c0 = ct * 64;
#pragma unroll
    for (int it = 0; it < 4; ++it) {
        const int idx = it * 256 + t;
        const int jl  = idx >> 4;
        const int cl4 = (idx & 15) * 4;
        *(float4*)&s[jl][cl4] =
            *(const float4*)(xv + ((size_t)b * N_ + j0 + jl) * C_ + c0 + cl4);
    }
    __syncthreads();
#pragma unroll
    for (int it = 0; it < 4; ++it) {
        const int cl = it * 16 + (t >> 4);
        const int j4 = (t & 15) * 4;
        ushort4 o;
        o.x = f2bf(s[j4 + 0][cl]); o.y = f2bf(s[j4 + 1][cl]);
        o.z = f2bf(s[j4 + 2][cl]); o.w = f2bf(s[j4 + 3][cl]);
        *(ushort4*)(vt + ((size_t)b * C_ + c0 + cl) * N_ + j0 + j4) = o;
    }
}

// ---------- main: 512 blocks x 512 thr (8 waves), M=32, j-tile 128 ----------
// S: wave w = j-strip (16 cols), both m-tiles.
// PV: wave = (ctq = w&3 -> 64 ch, ksh = w>>2 -> 2 of 4 K-slices); 2-way O-reduce at end.
__global__ __launch_bounds__(512, 4) void attn_main(
    const float* __restrict__ g,  const float* __restrict__ x,
    const float* __restrict__ kk, float* __restrict__ out,
    const unsigned short* __restrict__ qbf,
    const unsigned short* __restrict__ pgbf,
    const unsigned short* __restrict__ vt)
{
    __shared__ unsigned short p_lds[2][32][132]; // 132-short stride: 8B-aligned rows, 4-way max on b64 reads
    __shared__ float s_red[32][260];
    __shared__ float s_l[32];

    const int t    = threadIdx.x;
    const int lane = t & 63;
    const int w    = t >> 6;
    const int l15  = lane & 15;
    const int quad = lane >> 4;

    // XCD swizzle: bids === x (mod 8) share one batch -> per-XCD L2 holds 1 batch's vt+q
    const int bid = blockIdx.x;
    const int b   = bid & 3;
    const int rg  = bid >> 2;          // 0..127
    const int i0  = rg * 32;
    const size_t rowbase = (size_t)b * N_ + i0;

    const int wsj = w;                 // S j-strip
    const int ctq = w & 3;             // PV channel quarter
    const int ksh = w >> 2;            // PV K-slice half

    if (t < 32) s_l[t] = 0.f;

    // ---- g passthrough: 32 rows x 256 ch ----
#pragma unroll
    for (int it = 0; it < 4; ++it) {
        const int row = it * 8 + w;
        const int c4  = lane * 4;
        const float4 gv = *(const float4*)(g + (rowbase + row) * C_ + c4);
        *(float4*)(out + (rowbase + row) * (2 * C_) + C_ + c4) = gv;
    }

    // ---- pg A-frags (2 m-tiles x 2 K-slices), reused all tiles ----
    bf16x8 pgf[2][2];
#pragma unroll
    for (int mt = 0; mt < 2; ++mt)
#pragma unroll
        for (int ks = 0; ks < 2; ++ks)
            pgf[mt][ks] = *(const bf16x8*)(pgbf +
                (rowbase + mt * 16 + l15) * D_ + ks * 32 + quad * 8);

    f32x4 oacc[2][4];
#pragma unroll
    for (int mt = 0; mt < 2; ++mt)
#pragma unroll
        for (int ct = 0; ct < 4; ++ct) oacc[mt][ct] = (f32x4){0.f, 0.f, 0.f, 0.f};
    float ls[2][4] = {{0.f,0.f,0.f,0.f},{0.f,0.f,0.f,0.f}};

    const unsigned short* qb  = qbf + (size_t)b * N_ * D_;
    const unsigned short* vtb = vt  + (size_t)b * C_ * N_;

    __syncthreads();   // s_l zero visible; aligns waves before K-loop

    for (int jt = 0; jt < 32; ++jt) {
        const int j0  = jt * 128;
        const int buf = jt & 1;

        // prefetch first ct-pair of V B-frags for both K-slices (covered by S phase)
        bf16x8 vfp[2][2];
#pragma unroll
        for (int kp = 0; kp < 2; ++kp)
#pragma unroll
            for (int c2 = 0; c2 < 2; ++c2)
                vfp[kp][c2] = *(const bf16x8*)(vtb +
                    (size_t)(ctq * 64 + c2 * 16 + l15) * N_ +
                    j0 + (ksh * 2 + kp) * 32 + quad * 8);

        // ---- S for this wave's 16-j strip ----
        f32x4 sacc[2];
        sacc[0] = (f32x4){0.f,0.f,0.f,0.f};
        sacc[1] = (f32x4){0.f,0.f,0.f,0.f};
#pragma unroll
        for (int ks = 0; ks < 2; ++ks) {
            const bf16x8 qf = *(const bf16x8*)(qb +
                (size_t)(j0 + wsj * 16 + l15) * D_ + ks * 32 + quad * 8);
            sacc[0] = __builtin_amdgcn_mfma_f32_16x16x32_bf16(pgf[0][ks], qf, sacc[0], 0, 0, 0);
            sacc[1] = __builtin_amdgcn_mfma_f32_16x16x32_bf16(pgf[1][ks], qf, sacc[1], 0, 0, 0);
        }
#pragma unroll
        for (int mt = 0; mt < 2; ++mt)
#pragma unroll
            for (int r = 0; r < 4; ++r) {
                const float p = __expf(sacc[mt][r]);   // |s|<~50: no max-sub needed in fp32
                ls[mt][r] += p;
                p_lds[buf][mt * 16 + quad * 4 + r][wsj * 16 + l15] = f2bf(p);
            }
        __syncthreads();

        // ---- PV: O += P.V over this wave's 2 K-slices x 64 ch ----
#pragma unroll
        for (int kp = 0; kp < 2; ++kp) {
            const int kk2 = (ksh * 2 + kp) * 32;
            frag_u pa[2];
#pragma unroll
            for (int mt = 0; mt < 2; ++mt) {
                const unsigned short* prow = &p_lds[buf][mt * 16 + l15][kk2 + quad * 8];
                const uint2 lo = *(const uint2*)prow;
                const uint2 hi = *(const uint2*)(prow + 4);
                pa[mt].u[0] = lo.x; pa[mt].u[1] = lo.y;
                pa[mt].u[2] = hi.x; pa[mt].u[3] = hi.y;
            }
            // ct pair 0,1 (prefetched)
#pragma unroll
            for (int c2 = 0; c2 < 2; ++c2) {
                oacc[0][c2] = __builtin_amdgcn_mfma_f32_16x16x32_bf16(pa[0].f, vfp[kp][c2], oacc[0][c2], 0, 0, 0);
                oacc[1][c2] = __builtin_amdgcn_mfma_f32_16x16x32_bf16(pa[1].f, vfp[kp][c2], oacc[1][c2], 0, 0, 0);
            }
            // ct pair 2,3 (load now)
#pragma unroll
            for (int c2 = 0; c2 < 2; ++c2) {
                const bf16x8 vf = *(const bf16x8*)(vtb +
                    (size_t)(ctq * 64 + (2 + c2) * 16 + l15) * N_ + j0 + kk2 + quad * 8);
                oacc[0][2 + c2] = __builtin_amdgcn_mfma_f32_16x16x32_bf16(pa[0].f, vf, oacc[0][2 + c2], 0, 0, 0);
                oacc[1][2 + c2] = __builtin_amdgcn_mfma_f32_16x16x32_bf16(pa[1].f, vf, oacc[1][2 + c2], 0, 0, 0);
            }
        }
    }

    // ---- l: reduce 16 j-lanes, then 8 strips via LDS atomics ----
#pragma unroll
    for (int mt = 0; mt < 2; ++mt)
#pragma unroll
        for (int r = 0; r < 4; ++r) {
            float s = ls[mt][r];
            s += __shfl_xor(s, 1); s += __shfl_xor(s, 2);
            s += __shfl_xor(s, 4); s += __shfl_xor(s, 8);
            if (l15 == 0) atomicAdd(&s_l[mt * 16 + quad * 4 + r], s);
        }

    // ---- O: 2-way ks reduction ----
    if (ksh == 1) {
#pragma unroll
        for (int mt = 0; mt < 2; ++mt)
#pragma unroll
            for (int ct = 0; ct < 4; ++ct)
#pragma unroll
                for (int r = 0; r < 4; ++r)
                    s_red[mt * 16 + quad * 4 + r][ctq * 64 + ct * 16 + l15] = oacc[mt][ct][r];
    }
    __syncthreads();

    if (ksh == 0) {
        const float kval = kk[0];
#pragma unroll
        for (int mt = 0; mt < 2; ++mt)
#pragma unroll
            for (int r = 0; r < 4; ++r) {
                const int m = mt * 16 + quad * 4 + r;
                const float linv = 1.f / s_l[m];
                const size_t row = rowbase + m;
#pragma unroll
                for (int ct = 0; ct < 4; ++ct) {
                    const int c = ctq * 64 + ct * 16 + l15;
                    const float o = oacc[mt][ct][r] + s_red[m][c];
                    out[row * (2 * C_) + c] = kval * (o * linv) + x[row * C_ + c];
                }
            }
    }
}

// ---------- fallback (round-2 vector kernel) if workspace too small ----------
#define ROWS 4
#define FNT  256
__global__ __launch_bounds__(FNT, 2) void attn_fallback(
    const float* __restrict__ g, const float* __restrict__ x,
    const float* __restrict__ xq, const float* __restrict__ pg,
    const float* __restrict__ xv, const float* __restrict__ kk,
    float* __restrict__ out)
{
    __shared__ __align__(16) float s_pg[ROWS][D_];
    __shared__ __align__(16) float s_sc[N_ * ROWS];
    __shared__ float s_rmax[4][ROWS];
    __shared__ float s_rsum[4][ROWS];

    const int t = threadIdx.x, lane = t & 63, w = t >> 6, blk = blockIdx.x;
    const int b = blk >> 10, i0 = (blk & 1023) * ROWS;
    const size_t rowbase = (size_t)b * N_ + i0;
    {
        const int r = t >> 6, cc = (t & 63) * 4;
        const float4 gv = *(const float4*)(g + (rowbase + r) * C_ + cc);
        *(float4*)(out + (rowbase + r) * (2 * C_) + C_ + cc) = gv;
    }
    { const int r = t >> 6, d = t & 63; s_pg[r][d] = pg[(rowbase + r) * D_ + d]; }
    __syncthreads();
    const float* qb = xq + (size_t)b * N_ * D_;
    float lmax[ROWS];
#pragma unroll
    for (int r = 0; r < ROWS; ++r) lmax[r] = -1e30f;
    for (int jj = 0; jj < N_ / FNT; ++jj) {
        const int j = t + jj * FNT;
        const float4* q4p = (const float4*)(qb + (size_t)j * D_);
        float s[ROWS] = {0.f, 0.f, 0.f, 0.f};
#pragma unroll
        for (int u = 0; u < D_ / 8; ++u) {
            const float4 qa = q4p[u * 2], qc = q4p[u * 2 + 1];
#pragma unroll
            for (int r = 0; r < ROWS; ++r) {
                const float4 pa = *(const float4*)&s_pg[r][u * 8];
                const float4 pb = *(const float4*)&s_pg[r][u * 8 + 4];
                s[r] += qa.x * pa.x + qa.y * pa.y + qa.z * pa.z + qa.w * pa.w
                      + qc.x * pb.x + qc.y * pb.y + qc.z * pb.z + qc.w * pb.w;
            }
        }
        *(float4*)&s_sc[j * ROWS] = make_float4(s[0], s[1], s[2], s[3]);
#pragma unroll
        for (int r = 0; r < ROWS; ++r) lmax[r] = fmaxf(lmax[r], s[r]);
    }
#pragma unroll
    for (int r = 0; r < ROWS; ++r) {
        float m = lmax[r];
        for (int o = 32; o > 0; o >>= 1) m = fmaxf(m, __shfl_down(m, o));
        if (lane == 0) s_rmax[w][r] = m;
    }
    __syncthreads();
    float bmax[ROWS];
#pragma unroll
    for (int r = 0; r < ROWS; ++r)
        bmax[r] = fmaxf(fmaxf(s_rmax[0][r], s_rmax[1][r]), fmaxf(s_rmax[2][r], s_rmax[3][r]));
    float lsum[ROWS] = {0.f, 0.f, 0.f, 0.f};
    for (int jj = 0; jj < N_ / FNT; ++jj) {
        const int j = t + jj * FNT;
        float4 s4 = *(const float4*)&s_sc[j * ROWS];
        s4.x = __expf(s4.x - bmax[0]); s4.y = __expf(s4.y - bmax[1]);
        s4.z = __expf(s4.z - bmax[2]); s4.w = __expf(s4.w - bmax[3]);
        *(float4*)&s_sc[j * ROWS] = s4;
        lsum[0] += s4.x; lsum[1] += s4.y; lsum[2] += s4.z; lsum[3] += s4.w;
    }
#pragma unroll
    for (int r = 0; r < ROWS; ++r) {
        float sm = lsum[r];
        for (int o = 32; o > 0; o >>= 1) sm += __shfl_down(sm, o);
        if (lane == 0) s_rsum[w][r] = sm;
    }
    __syncthreads();
    float rinv[ROWS];
#pragma unroll
    for (int r = 0; r < ROWS; ++r)
        rinv[r] = 1.f / (s_rsum[0][r] + s_rsum[1][r] + s_rsum[2][r] + s_rsum[3][r]);
    const int jg = lane >> 4;
    const int c0 = (w * 16 + (lane & 15)) * 4;
    const float* vb = xv + (size_t)b * N_ * C_;
    float acc[ROWS][4];
#pragma unroll
    for (int r = 0; r < ROWS; ++r)
#pragma unroll
        for (int q = 0; q < 4; ++q) acc[r][q] = 0.f;
#pragma unroll 4
    for (int jj = 0; jj < N_ / 4; ++jj) {
        const int j = jj * 4 + jg;
        const float4 p4 = *(const float4*)&s_sc[j * ROWS];
        const float4 v4 = *(const float4*)(vb + (size_t)j * C_ + c0);
        acc[0][0] += p4.x * v4.x; acc[0][1] += p4.x * v4.y; acc[0][2] += p4.x * v4.z; acc[0][3] += p4.x * v4.w;
        acc[1][0] += p4.y * v4.x; acc[1][1] += p4.y * v4.y; acc[1][2] += p4.y * v4.z; acc[1][3] += p4.y * v4.w;
        acc[2][0] += p4.z * v4.x; acc[2][1] += p4.z * v4.y; acc[2][2] += p4.z * v4.z; acc[2][3] += p4.z * v4.w;
        acc[3][0] += p4.w * v4.x; acc[3][1] += p4.w * v4.y; acc[3][2] += p4.w * v4.z; acc[3][3] += p4.w * v4.w;
    }
#pragma unroll
    for (int r = 0; r < ROWS; ++r)
#pragma unroll
        for (int q = 0; q < 4; ++q) {
            acc[r][q] += __shfl_xor(acc[r][q], 16);
            acc[r][q] += __shfl_xor(acc[r][q], 32);
        }
    const float kval = kk[0];
    if (lane < 16) {
        const int c = (w * 16 + lane) * 4;
#pragma unroll
        for (int r = 0; r < ROWS; ++r) {
            const float4 xv4 = *(const float4*)(x + (rowbase + r) * C_ + c);
            float4 ov;
            ov.x = kval * (acc[r][0] * rinv[r]) + xv4.x;
            ov.y = kval * (acc[r][1] * rinv[r]) + xv4.y;
            ov.z = kval * (acc[r][2] * rinv[r]) + xv4.z;
            ov.w = kval * (acc[r][3] * rinv[r]) + xv4.w;
            *(float4*)(out + (rowbase + r) * (2 * C_) + c) = ov;
        }
    }
}

extern "C" void kernel_launch(void* const* d_in, const int* in_sizes, int n_in,
                              void* d_out, int out_size, void* d_ws, size_t ws_size,
                              hipStream_t stream) {
    const float* g  = (const float*)d_in[0];
    const float* x  = (const float*)d_in[1];
    const float* xq = (const float*)d_in[2];
    const float* pg = (const float*)d_in[3];
    const float* xv = (const float*)d_in[4];
    const float* kk = (const float*)d_in[5];
    float* out = (float*)d_out;

    const int B = in_sizes[0] / (N_ * C_);   // 4
    const size_t qn = (size_t)B * N_ * D_;
    const size_t vn = (size_t)B * N_ * C_;
    const size_t need = (2 * qn + vn) * sizeof(unsigned short);

    if (ws_size < need) {
        attn_fallback<<<dim3(B * (N_ / ROWS)), FNT, 0, stream>>>(g, x, xq, pg, xv, kk, out);
        return;
    }

    unsigned short* qbf  = (unsigned short*)d_ws;
    unsigned short* pgbf = qbf + qn;
    unsigned short* vtw  = pgbf + qn;

    prepass_kernel<<<dim3(512 + B * 256), 256, 0, stream>>>(xq, pg, xv, qbf, pgbf, vtw);
    attn_main<<<dim3(B * (N_ / 32)), 512, 0, stream>>>(g, x, kk, out, qbf, pgbf, vtw);
}

// Round 6
// 175.439 us; speedup vs baseline: 2.4712x; 1.4368x over previous
//
#include <hip/hip_runtime.h>

#define N_  4096
#define D_  64
#define C_  256

typedef short bf16x8 __attribute__((ext_vector_type(8)));
typedef float f32x4  __attribute__((ext_vector_type(4)));

__device__ __forceinline__ unsigned short f2bf(float f) {
    union { float f; unsigned int i; } v; v.f = f;
    unsigned int r = v.i + 0x7fffu + ((v.i >> 16) & 1u);
    return (unsigned short)(r >> 16);
}

// ---------- fused prepass ----------
// blocks [0,256): q->bf16 ; [256,512): pg->bf16 ;
// [512,1024): v -> vt2 in MFMA-B-frag order:
//   vt2[((b*32+jt)*16 + cb)*4 + ks][lane*8 + e] = v[b][jt*128 + ks*32 + (lane>>4)*8 + e][cb*16 + (lane&15)]
// Every 16x32 fragment is a contiguous 1KB block -> coalesced reads in main, no L2 channel camping.
__global__ void prepass_kernel(const float* __restrict__ xq,
                               const float* __restrict__ pg,
                               const float* __restrict__ xv,
                               unsigned short* __restrict__ qbf,
                               unsigned short* __restrict__ pgbf,
                               unsigned short* __restrict__ vt2) {
    __shared__ float s[128][65];
    const int bid = blockIdx.x;
    const int t   = threadIdx.x;
    if (bid < 512) {
        const float* src = (bid < 256) ? xq : pg;
        unsigned short* dst = (bid < 256) ? qbf : pgbf;
        const int base = (bid & 255) * 1024 + t;
#pragma unroll
        for (int it = 0; it < 4; ++it) {
            const int i = base + it * 256;
            float4 v = ((const float4*)src)[i];
            ushort4 o;
            o.x = f2bf(v.x); o.y = f2bf(v.y); o.z = f2bf(v.z); o.w = f2bf(v.w);
            ((ushort4*)dst)[i] = o;
        }
        return;
    }
    // V re-layout: block = (b, jt, cq); 128 j x 64 c staged in LDS.
    const int tb = bid - 512;            // 0..511
    const int b  = tb >> 7;
    const int jt = (tb >> 2) & 31;
    const int cq = tb & 3;
    const int j0 = jt * 128, c0 = cq * 64;
#pragma unroll
    for (int it = 0; it < 8; ++it) {
        const int idx = it * 256 + t;    // 0..2047
        const int jl  = idx >> 4;        // 0..127
        const int cl4 = (idx & 15) * 4;
        *(float4*)&s[jl][cl4] =
            *(const float4*)(xv + ((size_t)b * N_ + j0 + jl) * C_ + c0 + cl4);
    }
    __syncthreads();
    // emit 16 frags (cbl 0..3 x ks 0..3), 1KB each, coalesced ushort4 writes
    unsigned short* outb = vt2 + ((((size_t)b * 32 + jt) * 16 + cq * 4) * 4) * 512;
#pragma unroll
    for (int it = 0; it < 8; ++it) {
        const int ci   = it * 256 + t;   // ushort4 index 0..2047
        const int frag = ci >> 7;        // cbl*4 + ks
        const int rem  = ci & 127;
        const int L    = rem >> 1;
        const int eh   = (rem & 1) * 4;
        const int cbl  = frag >> 2, ks = frag & 3;
        const int cl   = cbl * 16 + (L & 15);
        const int jl   = ks * 32 + (L >> 4) * 8 + eh;
        ushort4 o;
        o.x = f2bf(s[jl + 0][cl]); o.y = f2bf(s[jl + 1][cl]);
        o.z = f2bf(s[jl + 2][cl]); o.w = f2bf(s[jl + 3][cl]);
        ((ushort4*)outb)[ci] = o;
    }
}

// ---------- main: 512 blocks x 512 thr (8 waves), M=32, j-tile 128 ----------
// S: wave w = 16-j strip, both m-tiles. PV: wave = (ctq = w&3 -> 64 ch, ksh = w>>2).
__global__ __launch_bounds__(512, 4) void attn_main(
    const float* __restrict__ g,  const float* __restrict__ x,
    const float* __restrict__ kk, float* __restrict__ out,
    const unsigned short* __restrict__ qbf,
    const unsigned short* __restrict__ pgbf,
    const unsigned short* __restrict__ vt2)
{
    __shared__ unsigned short p_lds[2][32][132]; // 8B-aligned rows, <=4-way on b64 reads (0 measured)
    __shared__ float s_red[32][260];
    __shared__ float s_l[32];

    const int t    = threadIdx.x;
    const int lane = t & 63;
    const int w    = t >> 6;
    const int l15  = lane & 15;
    const int quad = lane >> 4;

    const int bid = blockIdx.x;
    const int b   = bid & 3;            // batch pinned to 2 XCDs
    const int rg  = bid >> 2;           // 0..127
    const int i0  = rg * 32;
    const size_t rowbase = (size_t)b * N_ + i0;

    const int wsj = w;
    const int ctq = w & 3;
    const int ksh = w >> 2;

    if (t < 32) s_l[t] = 0.f;

    // ---- g passthrough ----
#pragma unroll
    for (int it = 0; it < 4; ++it) {
        const int row = it * 8 + w;
        const int c4  = lane * 4;
        const float4 gv = *(const float4*)(g + (rowbase + row) * C_ + c4);
        *(float4*)(out + (rowbase + row) * (2 * C_) + C_ + c4) = gv;
    }

    // ---- pg A-frags ----
    bf16x8 pgf[2][2];
#pragma unroll
    for (int mt = 0; mt < 2; ++mt)
#pragma unroll
        for (int ks = 0; ks < 2; ++ks)
            pgf[mt][ks] = *(const bf16x8*)(pgbf +
                (rowbase + mt * 16 + l15) * D_ + ks * 32 + quad * 8);

    f32x4 oacc[2][4];
#pragma unroll
    for (int mt = 0; mt < 2; ++mt)
#pragma unroll
        for (int ct = 0; ct < 4; ++ct) oacc[mt][ct] = (f32x4){0.f, 0.f, 0.f, 0.f};
    float ls[2][4] = {{0.f,0.f,0.f,0.f},{0.f,0.f,0.f,0.f}};

    const unsigned short* qb  = qbf + (size_t)b * N_ * D_;
    const unsigned short* vtb = vt2 + (size_t)b * N_ * C_;   // frag-linear per batch

    __syncthreads();

    for (int jt = 0; jt < 32; ++jt) {
        const int j0  = jt * 128;
        const int buf = jt & 1;
        const unsigned short* tbase = vtb + (size_t)jt * 32768;  // 16 cb x 4 ks x 512

        // prefetch ALL 8 V B-frags for this tile (1KB contiguous each, lane*16B)
        bf16x8 vfp[2][4];
#pragma unroll
        for (int kp = 0; kp < 2; ++kp)
#pragma unroll
            for (int c2 = 0; c2 < 4; ++c2)
                vfp[kp][c2] = *(const bf16x8*)(tbase +
                    (size_t)(((ctq * 4 + c2) * 4) + (ksh * 2 + kp)) * 512 + lane * 8);

        // ---- S for this wave's 16-j strip ----
        f32x4 sacc[2];
        sacc[0] = (f32x4){0.f,0.f,0.f,0.f};
        sacc[1] = (f32x4){0.f,0.f,0.f,0.f};
#pragma unroll
        for (int ks = 0; ks < 2; ++ks) {
            const bf16x8 qf = *(const bf16x8*)(qb +
                (size_t)(j0 + wsj * 16 + l15) * D_ + ks * 32 + quad * 8);
            sacc[0] = __builtin_amdgcn_mfma_f32_16x16x32_bf16(pgf[0][ks], qf, sacc[0], 0, 0, 0);
            sacc[1] = __builtin_amdgcn_mfma_f32_16x16x32_bf16(pgf[1][ks], qf, sacc[1], 0, 0, 0);
        }
#pragma unroll
        for (int mt = 0; mt < 2; ++mt)
#pragma unroll
            for (int r = 0; r < 4; ++r) {
                const float p = __expf(sacc[mt][r]);   // |s| small: no max-sub needed in fp32
                ls[mt][r] += p;
                p_lds[buf][mt * 16 + quad * 4 + r][wsj * 16 + l15] = f2bf(p);
            }
        __syncthreads();

        // ---- PV: O += P.V over this wave's 2 K-slices x 64 ch ----
#pragma unroll
        for (int kp = 0; kp < 2; ++kp) {
            const int kk2 = (ksh * 2 + kp) * 32;
            union { bf16x8 f; uint2 u2[2]; } pa[2];
#pragma unroll
            for (int mt = 0; mt < 2; ++mt) {
                const unsigned short* prow = &p_lds[buf][mt * 16 + l15][kk2 + quad * 8];
                pa[mt].u2[0] = *(const uint2*)prow;
                pa[mt].u2[1] = *(const uint2*)(prow + 4);
            }
#pragma unroll
            for (int c2 = 0; c2 < 4; ++c2) {
                oacc[0][c2] = __builtin_amdgcn_mfma_f32_16x16x32_bf16(pa[0].f, vfp[kp][c2], oacc[0][c2], 0, 0, 0);
                oacc[1][c2] = __builtin_amdgcn_mfma_f32_16x16x32_bf16(pa[1].f, vfp[kp][c2], oacc[1][c2], 0, 0, 0);
            }
        }
    }

    // ---- l reduction ----
#pragma unroll
    for (int mt = 0; mt < 2; ++mt)
#pragma unroll
        for (int r = 0; r < 4; ++r) {
            float s = ls[mt][r];
            s += __shfl_xor(s, 1); s += __shfl_xor(s, 2);
            s += __shfl_xor(s, 4); s += __shfl_xor(s, 8);
            if (l15 == 0) atomicAdd(&s_l[mt * 16 + quad * 4 + r], s);
        }

    // ---- O: 2-way ks reduction ----
    if (ksh == 1) {
#pragma unroll
        for (int mt = 0; mt < 2; ++mt)
#pragma unroll
            for (int ct = 0; ct < 4; ++ct)
#pragma unroll
                for (int r = 0; r < 4; ++r)
                    s_red[mt * 16 + quad * 4 + r][ctq * 64 + ct * 16 + l15] = oacc[mt][ct][r];
    }
    __syncthreads();

    if (ksh == 0) {
        const float kval = kk[0];
#pragma unroll
        for (int mt = 0; mt < 2; ++mt)
#pragma unroll
            for (int r = 0; r < 4; ++r) {
                const int m = mt * 16 + quad * 4 + r;
                const float linv = 1.f / s_l[m];
                const size_t row = rowbase + m;
#pragma unroll
                for (int ct = 0; ct < 4; ++ct) {
                    const int c = ctq * 64 + ct * 16 + l15;
                    const float o = oacc[mt][ct][r] + s_red[m][c];
                    out[row * (2 * C_) + c] = kval * (o * linv) + x[row * C_ + c];
                }
            }
    }
}

// ---------- fallback (round-2 vector kernel) if workspace too small ----------
#define ROWS 4
#define FNT  256
__global__ __launch_bounds__(FNT, 2) void attn_fallback(
    const float* __restrict__ g, const float* __restrict__ x,
    const float* __restrict__ xq, const float* __restrict__ pg,
    const float* __restrict__ xv, const float* __restrict__ kk,
    float* __restrict__ out)
{
    __shared__ __align__(16) float s_pg[ROWS][D_];
    __shared__ __align__(16) float s_sc[N_ * ROWS];
    __shared__ float s_rmax[4][ROWS];
    __shared__ float s_rsum[4][ROWS];

    const int t = threadIdx.x, lane = t & 63, w = t >> 6, blk = blockIdx.x;
    const int b = blk >> 10, i0 = (blk & 1023) * ROWS;
    const size_t rowbase = (size_t)b * N_ + i0;
    {
        const int r = t >> 6, cc = (t & 63) * 4;
        const float4 gv = *(const float4*)(g + (rowbase + r) * C_ + cc);
        *(float4*)(out + (rowbase + r) * (2 * C_) + C_ + cc) = gv;
    }
    { const int r = t >> 6, d = t & 63; s_pg[r][d] = pg[(rowbase + r) * D_ + d]; }
    __syncthreads();
    const float* qb = xq + (size_t)b * N_ * D_;
    float lmax[ROWS];
#pragma unroll
    for (int r = 0; r < ROWS; ++r) lmax[r] = -1e30f;
    for (int jj = 0; jj < N_ / FNT; ++jj) {
        const int j = t + jj * FNT;
        const float4* q4p = (const float4*)(qb + (size_t)j * D_);
        float s[ROWS] = {0.f, 0.f, 0.f, 0.f};
#pragma unroll
        for (int u = 0; u < D_ / 8; ++u) {
            const float4 qa = q4p[u * 2], qc = q4p[u * 2 + 1];
#pragma unroll
            for (int r = 0; r < ROWS; ++r) {
                const float4 pa = *(const float4*)&s_pg[r][u * 8];
                const float4 pb = *(const float4*)&s_pg[r][u * 8 + 4];
                s[r] += qa.x * pa.x + qa.y * pa.y + qa.z * pa.z + qa.w * pa.w
                      + qc.x * pb.x + qc.y * pb.y + qc.z * pb.z + qc.w * pb.w;
            }
        }
        *(float4*)&s_sc[j * ROWS] = make_float4(s[0], s[1], s[2], s[3]);
#pragma unroll
        for (int r = 0; r < ROWS; ++r) lmax[r] = fmaxf(lmax[r], s[r]);
    }
#pragma unroll
    for (int r = 0; r < ROWS; ++r) {
        float m = lmax[r];
        for (int o = 32; o > 0; o >>= 1) m = fmaxf(m, __shfl_down(m, o));
        if (lane == 0) s_rmax[w][r] = m;
    }
    __syncthreads();
    float bmax[ROWS];
#pragma unroll
    for (int r = 0; r < ROWS; ++r)
        bmax[r] = fmaxf(fmaxf(s_rmax[0][r], s_rmax[1][r]), fmaxf(s_rmax[2][r], s_rmax[3][r]));
    float lsum[ROWS] = {0.f, 0.f, 0.f, 0.f};
    for (int jj = 0; jj < N_ / FNT; ++jj) {
        const int j = t + jj * FNT;
        float4 s4 = *(const float4*)&s_sc[j * ROWS];
        s4.x = __expf(s4.x - bmax[0]); s4.y = __expf(s4.y - bmax[1]);
        s4.z = __expf(s4.z - bmax[2]); s4.w = __expf(s4.w - bmax[3]);
        *(float4*)&s_sc[j * ROWS] = s4;
        lsum[0] += s4.x; lsum[1] += s4.y; lsum[2] += s4.z; lsum[3] += s4.w;
    }
#pragma unroll
    for (int r = 0; r < ROWS; ++r) {
        float sm = lsum[r];
        for (int o = 32; o > 0; o >>= 1) sm += __shfl_down(sm, o);
        if (lane == 0) s_rsum[w][r] = sm;
    }
    __syncthreads();
    float rinv[ROWS];
#pragma unroll
    for (int r = 0; r < ROWS; ++r)
        rinv[r] = 1.f / (s_rsum[0][r] + s_rsum[1][r] + s_rsum[2][r] + s_rsum[3][r]);
    const int jg = lane >> 4;
    const int c0 = (w * 16 + (lane & 15)) * 4;
    const float* vb = xv + (size_t)b * N_ * C_;
    float acc[ROWS][4];
#pragma unroll
    for (int r = 0; r < ROWS; ++r)
#pragma unroll
        for (int q = 0; q < 4; ++q) acc[r][q] = 0.f;
#pragma unroll 4
    for (int jj = 0; jj < N_ / 4; ++jj) {
        const int j = jj * 4 + jg;
        const float4 p4 = *(const float4*)&s_sc[j * ROWS];
        const float4 v4 = *(const float4*)(vb + (size_t)j * C_ + c0);
        acc[0][0] += p4.x * v4.x; acc[0][1] += p4.x * v4.y; acc[0][2] += p4.x * v4.z; acc[0][3] += p4.x * v4.w;
        acc[1][0] += p4.y * v4.x; acc[1][1] += p4.y * v4.y; acc[1][2] += p4.y * v4.z; acc[1][3] += p4.y * v4.w;
        acc[2][0] += p4.z * v4.x; acc[2][1] += p4.z * v4.y; acc[2][2] += p4.z * v4.z; acc[2][3] += p4.z * v4.w;
        acc[3][0] += p4.w * v4.x; acc[3][1] += p4.w * v4.y; acc[3][2] += p4.w * v4.z; acc[3][3] += p4.w * v4.w;
    }
#pragma unroll
    for (int r = 0; r < ROWS; ++r)
#pragma unroll
        for (int q = 0; q < 4; ++q) {
            acc[r][q] += __shfl_xor(acc[r][q], 16);
            acc[r][q] += __shfl_xor(acc[r][q], 32);
        }
    const float kval = kk[0];
    if (lane < 16) {
        const int c = (w * 16 + lane) * 4;
#pragma unroll
        for (int r = 0; r < ROWS; ++r) {
            const float4 xv4 = *(const float4*)(x + (rowbase + r) * C_ + c);
            float4 ov;
            ov.x = kval * (acc[r][0] * rinv[r]) + xv4.x;
            ov.y = kval * (acc[r][1] * rinv[r]) + xv4.y;
            ov.z = kval * (acc[r][2] * rinv[r]) + xv4.z;
            ov.w = kval * (acc[r][3] * rinv[r]) + xv4.w;
            *(float4*)(out + (rowbase + r) * (2 * C_) + c) = ov;
        }
    }
}

extern "C" void kernel_launch(void* const* d_in, const int* in_sizes, int n_in,
                              void* d_out, int out_size, void* d_ws, size_t ws_size,
                              hipStream_t stream) {
    const float* g  = (const float*)d_in[0];
    const float* x  = (const float*)d_in[1];
    const float* xq = (const float*)d_in[2];
    const float* pg = (const float*)d_in[3];
    const float* xv = (const float*)d_in[4];
    const float* kk = (const float*)d_in[5];
    float* out = (float*)d_out;

    const int B = in_sizes[0] / (N_ * C_);   // 4
    const size_t qn = (size_t)B * N_ * D_;
    const size_t vn = (size_t)B * N_ * C_;
    const size_t need = (2 * qn + vn) * sizeof(unsigned short);

    if (ws_size < need) {
        attn_fallback<<<dim3(B * (N_ / ROWS)), FNT, 0, stream>>>(g, x, xq, pg, xv, kk, out);
        return;
    }

    unsigned short* qbf  = (unsigned short*)d_ws;
    unsigned short* pgbf = qbf + qn;
    unsigned short* vt2  = pgbf + qn;

    prepass_kernel<<<dim3(512 + B * 128), 256, 0, stream>>>(xq, pg, xv, qbf, pgbf, vt2);
    attn_main<<<dim3(B * (N_ / 32)), 512, 0, stream>>>(g, x, kk, out, qbf, pgbf, vt2);
}

// Round 7
// 173.257 us; speedup vs baseline: 2.5023x; 1.0126x over previous
//
#include <hip/hip_runtime.h>

#define N_  4096
#define D_  64
#define C_  256

typedef short bf16x8 __attribute__((ext_vector_type(8)));
typedef float f32x4  __attribute__((ext_vector_type(4)));

__device__ __forceinline__ unsigned short f2bf(float f) {
    union { float f; unsigned int i; } v; v.f = f;
    unsigned int r = v.i + 0x7fffu + ((v.i >> 16) & 1u);
    return (unsigned short)(r >> 16);
}

// ---------- fused prepass (no LDS, max occupancy) ----------
// blocks [0,256): q->bf16 ; [256,512): pg->bf16 ;
// blocks [512, 512+2048): v -> vt2 in MFMA-B-frag order, ONE WAVE PER FRAGMENT.
//   frag f = ((b*32 + jt)*16 + cb)*4 + ks  (512 shorts, contiguous 1KB)
//   vt2[f*512 + lane*8 + e] = v[b][jt*128 + ks*32 + (lane>>4)*8 + e][cb*16 + (lane&15)]
__global__ void prepass_kernel(const float* __restrict__ xq,
                               const float* __restrict__ pg,
                               const float* __restrict__ xv,
                               unsigned short* __restrict__ qbf,
                               unsigned short* __restrict__ pgbf,
                               unsigned short* __restrict__ vt2) {
    const int bid = blockIdx.x;
    const int t   = threadIdx.x;
    if (bid < 512) {
        const float* src = (bid < 256) ? xq : pg;
        unsigned short* dst = (bid < 256) ? qbf : pgbf;
        const int base = (bid & 255) * 1024 + t;
#pragma unroll
        for (int it = 0; it < 4; ++it) {
            const int i = base + it * 256;
            float4 v = ((const float4*)src)[i];
            ushort4 o;
            o.x = f2bf(v.x); o.y = f2bf(v.y); o.z = f2bf(v.z); o.w = f2bf(v.w);
            ((ushort4*)dst)[i] = o;
        }
        return;
    }
    // V fragment emit: 4 waves/block, one frag per wave
    const int lane = t & 63;
    const int w    = t >> 6;
    const int l15  = lane & 15;
    const int quad = lane >> 4;
    const int f    = (bid - 512) * 4 + w;        // 0..8191
    const int b    = f >> 11;
    const int jt   = (f >> 6) & 31;
    const int cb   = (f >> 2) & 15;
    const int ks   = f & 3;
    const int c    = cb * 16 + l15;
    const int jb   = jt * 128 + ks * 32 + quad * 8;
    const float* src = xv + ((size_t)b * N_ + jb) * C_ + c;
    float v0 = src[0 * C_], v1 = src[1 * C_], v2 = src[2 * C_], v3 = src[3 * C_];
    float v4 = src[4 * C_], v5 = src[5 * C_], v6 = src[6 * C_], v7 = src[7 * C_];
    uint4 o;
    o.x = (unsigned)f2bf(v0) | ((unsigned)f2bf(v1) << 16);
    o.y = (unsigned)f2bf(v2) | ((unsigned)f2bf(v3) << 16);
    o.z = (unsigned)f2bf(v4) | ((unsigned)f2bf(v5) << 16);
    o.w = (unsigned)f2bf(v6) | ((unsigned)f2bf(v7) << 16);
    *(uint4*)(vt2 + (size_t)f * 512 + lane * 8) = o;
}

// ---------- main: 256 blocks x 512 thr (8 waves), M=64, j-tile 128 ----------
// S: wave w = 16-j strip, all 4 m-tiles.
// PV: wave = (mh = w>>2 m-half, ctq = w&3 channel quarter), ALL 4 K-slices
//     -> each wave owns its O[2 mt][64 ch] completely; no O cross-wave reduction.
__global__ __launch_bounds__(512, 2) void attn_main(
    const float* __restrict__ g,  const float* __restrict__ x,
    const float* __restrict__ kk, float* __restrict__ out,
    const unsigned short* __restrict__ qbf,
    const unsigned short* __restrict__ pgbf,
    const unsigned short* __restrict__ vt2)
{
    __shared__ unsigned short p_lds[2][64][132]; // 8B-aligned rows; 0 conflicts measured on b64 reads
    __shared__ float s_l[64];

    const int t    = threadIdx.x;
    const int lane = t & 63;
    const int w    = t >> 6;
    const int l15  = lane & 15;
    const int quad = lane >> 4;

    const int bid = blockIdx.x;
    const int b   = bid & 3;            // batch pinned to 2 XCDs
    const int rg  = bid >> 2;           // 0..63
    const int i0  = rg * 64;
    const size_t rowbase = (size_t)b * N_ + i0;

    const int wsj = w;                  // S j-strip
    const int mh  = w >> 2;             // PV m-half
    const int ctq = w & 3;              // PV channel quarter

    if (t < 64) s_l[t] = 0.f;

    // ---- g passthrough: 64 rows x 256 ch ----
#pragma unroll
    for (int it = 0; it < 8; ++it) {
        const int row = it * 8 + w;
        const int c4  = lane * 4;
        const float4 gv = *(const float4*)(g + (rowbase + row) * C_ + c4);
        *(float4*)(out + (rowbase + row) * (2 * C_) + C_ + c4) = gv;
    }

    // ---- pg A-frags: 4 m-tiles x 2 K-slices, reused all tiles ----
    bf16x8 pgf[4][2];
#pragma unroll
    for (int mt = 0; mt < 4; ++mt)
#pragma unroll
        for (int ks = 0; ks < 2; ++ks)
            pgf[mt][ks] = *(const bf16x8*)(pgbf +
                (rowbase + mt * 16 + l15) * D_ + ks * 32 + quad * 8);

    f32x4 oacc[2][4];
#pragma unroll
    for (int mtl = 0; mtl < 2; ++mtl)
#pragma unroll
        for (int ct = 0; ct < 4; ++ct) oacc[mtl][ct] = (f32x4){0.f, 0.f, 0.f, 0.f};
    float ls[4][4];
#pragma unroll
    for (int mt = 0; mt < 4; ++mt)
#pragma unroll
        for (int r = 0; r < 4; ++r) ls[mt][r] = 0.f;

    const unsigned short* qb  = qbf + (size_t)b * N_ * D_;
    const unsigned short* vtb = vt2 + (size_t)b * N_ * C_;

    // q frags for tile 0
    bf16x8 qf[2];
#pragma unroll
    for (int ks = 0; ks < 2; ++ks)
        qf[ks] = *(const bf16x8*)(qb + (size_t)(wsj * 16 + l15) * D_ + ks * 32 + quad * 8);

    __syncthreads();

    for (int jt = 0; jt < 32; ++jt) {
        const int buf = jt & 1;
        const unsigned short* tbase = vtb + (size_t)jt * 32768;

        // prefetch all 16 V B-frags for this wave (1KB contiguous each; in flight during S)
        bf16x8 vfp[4][4];   // [ks][ct]
#pragma unroll
        for (int ks = 0; ks < 4; ++ks)
#pragma unroll
            for (int ct = 0; ct < 4; ++ct)
                vfp[ks][ct] = *(const bf16x8*)(tbase +
                    (size_t)(((ctq * 4 + ct) * 4) + ks) * 512 + lane * 8);

        // ---- S: 4 m-tiles for this wave's 16-j strip ----
        f32x4 sacc[4];
#pragma unroll
        for (int mt = 0; mt < 4; ++mt) sacc[mt] = (f32x4){0.f, 0.f, 0.f, 0.f};
#pragma unroll
        for (int ks = 0; ks < 2; ++ks)
#pragma unroll
            for (int mt = 0; mt < 4; ++mt)
                sacc[mt] = __builtin_amdgcn_mfma_f32_16x16x32_bf16(pgf[mt][ks], qf[ks], sacc[mt], 0, 0, 0);

#pragma unroll
        for (int mt = 0; mt < 4; ++mt)
#pragma unroll
            for (int r = 0; r < 4; ++r) {
                const float p = __expf(sacc[mt][r]);  // |s| small: fp32-safe w/o max-sub
                ls[mt][r] += p;
                p_lds[buf][mt * 16 + quad * 4 + r][wsj * 16 + l15] = f2bf(p);
            }
        __syncthreads();

        // next tile's q frags (issued before PV; in flight during PV MFMAs)
        if (jt < 31) {
            const int jn = (jt + 1) * 128;
#pragma unroll
            for (int ks = 0; ks < 2; ++ks)
                qf[ks] = *(const bf16x8*)(qb +
                    (size_t)(jn + wsj * 16 + l15) * D_ + ks * 32 + quad * 8);
        }

        // ---- PV: all 4 K-slices, 2 m-tiles x 4 c-tiles ----
#pragma unroll
        for (int ks = 0; ks < 4; ++ks) {
            union { bf16x8 f; uint2 u2[2]; } pa[2];
#pragma unroll
            for (int mtl = 0; mtl < 2; ++mtl) {
                const unsigned short* prow =
                    &p_lds[buf][(mh * 2 + mtl) * 16 + l15][ks * 32 + quad * 8];
                pa[mtl].u2[0] = *(const uint2*)prow;
                pa[mtl].u2[1] = *(const uint2*)(prow + 4);
            }
#pragma unroll
            for (int ct = 0; ct < 4; ++ct) {
                oacc[0][ct] = __builtin_amdgcn_mfma_f32_16x16x32_bf16(pa[0].f, vfp[ks][ct], oacc[0][ct], 0, 0, 0);
                oacc[1][ct] = __builtin_amdgcn_mfma_f32_16x16x32_bf16(pa[1].f, vfp[ks][ct], oacc[1][ct], 0, 0, 0);
            }
        }
    }

    // ---- l reduction: 16 j-lanes, then 8 strips via LDS atomics ----
#pragma unroll
    for (int mt = 0; mt < 4; ++mt)
#pragma unroll
        for (int r = 0; r < 4; ++r) {
            float s = ls[mt][r];
            s += __shfl_xor(s, 1); s += __shfl_xor(s, 2);
            s += __shfl_xor(s, 4); s += __shfl_xor(s, 8);
            if (l15 == 0) atomicAdd(&s_l[mt * 16 + quad * 4 + r], s);
        }
    __syncthreads();

    // ---- epilogue: each wave owns O[2 mt][64 ch] fully ----
    const float kval = kk[0];
#pragma unroll
    for (int mtl = 0; mtl < 2; ++mtl) {
        const int mt = mh * 2 + mtl;
#pragma unroll
        for (int r = 0; r < 4; ++r) {
            const int m = mt * 16 + quad * 4 + r;
            const float linv = 1.f / s_l[m];
            const size_t row = rowbase + m;
#pragma unroll
            for (int ct = 0; ct < 4; ++ct) {
                const int c = ctq * 64 + ct * 16 + l15;
                out[row * (2 * C_) + c] = kval * (oacc[mtl][ct][r] * linv) + x[row * C_ + c];
            }
        }
    }
}

// ---------- fallback (round-2 vector kernel) if workspace too small ----------
#define ROWS 4
#define FNT  256
__global__ __launch_bounds__(FNT, 2) void attn_fallback(
    const float* __restrict__ g, const float* __restrict__ x,
    const float* __restrict__ xq, const float* __restrict__ pg,
    const float* __restrict__ xv, const float* __restrict__ kk,
    float* __restrict__ out)
{
    __shared__ __align__(16) float s_pg[ROWS][D_];
    __shared__ __align__(16) float s_sc[N_ * ROWS];
    __shared__ float s_rmax[4][ROWS];
    __shared__ float s_rsum[4][ROWS];

    const int t = threadIdx.x, lane = t & 63, w = t >> 6, blk = blockIdx.x;
    const int b = blk >> 10, i0 = (blk & 1023) * ROWS;
    const size_t rowbase = (size_t)b * N_ + i0;
    {
        const int r = t >> 6, cc = (t & 63) * 4;
        const float4 gv = *(const float4*)(g + (rowbase + r) * C_ + cc);
        *(float4*)(out + (rowbase + r) * (2 * C_) + C_ + cc) = gv;
    }
    { const int r = t >> 6, d = t & 63; s_pg[r][d] = pg[(rowbase + r) * D_ + d]; }
    __syncthreads();
    const float* qb = xq + (size_t)b * N_ * D_;
    float lmax[ROWS];
#pragma unroll
    for (int r = 0; r < ROWS; ++r) lmax[r] = -1e30f;
    for (int jj = 0; jj < N_ / FNT; ++jj) {
        const int j = t + jj * FNT;
        const float4* q4p = (const float4*)(qb + (size_t)j * D_);
        float s[ROWS] = {0.f, 0.f, 0.f, 0.f};
#pragma unroll
        for (int u = 0; u < D_ / 8; ++u) {
            const float4 qa = q4p[u * 2], qc = q4p[u * 2 + 1];
#pragma unroll
            for (int r = 0; r < ROWS; ++r) {
                const float4 pa = *(const float4*)&s_pg[r][u * 8];
                const float4 pb = *(const float4*)&s_pg[r][u * 8 + 4];
                s[r] += qa.x * pa.x + qa.y * pa.y + qa.z * pa.z + qa.w * pa.w
                      + qc.x * pb.x + qc.y * pb.y + qc.z * pb.z + qc.w * pb.w;
            }
        }
        *(float4*)&s_sc[j * ROWS] = make_float4(s[0], s[1], s[2], s[3]);
#pragma unroll
        for (int r = 0; r < ROWS; ++r) lmax[r] = fmaxf(lmax[r], s[r]);
    }
#pragma unroll
    for (int r = 0; r < ROWS; ++r) {
        float m = lmax[r];
        for (int o = 32; o > 0; o >>= 1) m = fmaxf(m, __shfl_down(m, o));
        if (lane == 0) s_rmax[w][r] = m;
    }
    __syncthreads();
    float bmax[ROWS];
#pragma unroll
    for (int r = 0; r < ROWS; ++r)
        bmax[r] = fmaxf(fmaxf(s_rmax[0][r], s_rmax[1][r]), fmaxf(s_rmax[2][r], s_rmax[3][r]));
    float lsum[ROWS] = {0.f, 0.f, 0.f, 0.f};
    for (int jj = 0; jj < N_ / FNT; ++jj) {
        const int j = t + jj * FNT;
        float4 s4 = *(const float4*)&s_sc[j * ROWS];
        s4.x = __expf(s4.x - bmax[0]); s4.y = __expf(s4.y - bmax[1]);
        s4.z = __expf(s4.z - bmax[2]); s4.w = __expf(s4.w - bmax[3]);
        *(float4*)&s_sc[j * ROWS] = s4;
        lsum[0] += s4.x; lsum[1] += s4.y; lsum[2] += s4.z; lsum[3] += s4.w;
    }
#pragma unroll
    for (int r = 0; r < ROWS; ++r) {
        float sm = lsum[r];
        for (int o = 32; o > 0; o >>= 1) sm += __shfl_down(sm, o);
        if (lane == 0) s_rsum[w][r] = sm;
    }
    __syncthreads();
    float rinv[ROWS];
#pragma unroll
    for (int r = 0; r < ROWS; ++r)
        rinv[r] = 1.f / (s_rsum[0][r] + s_rsum[1][r] + s_rsum[2][r] + s_rsum[3][r]);
    const int jg = lane >> 4;
    const int c0 = (w * 16 + (lane & 15)) * 4;
    const float* vb = xv + (size_t)b * N_ * C_;
    float acc[ROWS][4];
#pragma unroll
    for (int r = 0; r < ROWS; ++r)
#pragma unroll
        for (int q = 0; q < 4; ++q) acc[r][q] = 0.f;
#pragma unroll 4
    for (int jj = 0; jj < N_ / 4; ++jj) {
        const int j = jj * 4 + jg;
        const float4 p4 = *(const float4*)&s_sc[j * ROWS];
        const float4 v4 = *(const float4*)(vb + (size_t)j * C_ + c0);
        acc[0][0] += p4.x * v4.x; acc[0][1] += p4.x * v4.y; acc[0][2] += p4.x * v4.z; acc[0][3] += p4.x * v4.w;
        acc[1][0] += p4.y * v4.x; acc[1][1] += p4.y * v4.y; acc[1][2] += p4.y * v4.z; acc[1][3] += p4.y * v4.w;
        acc[2][0] += p4.z * v4.x; acc[2][1] += p4.z * v4.y; acc[2][2] += p4.z * v4.z; acc[2][3] += p4.z * v4.w;
        acc[3][0] += p4.w * v4.x; acc[3][1] += p4.w * v4.y; acc[3][2] += p4.w * v4.z; acc[3][3] += p4.w * v4.w;
    }
#pragma unroll
    for (int r = 0; r < ROWS; ++r)
#pragma unroll
        for (int q = 0; q < 4; ++q) {
            acc[r][q] += __shfl_xor(acc[r][q], 16);
            acc[r][q] += __shfl_xor(acc[r][q], 32);
        }
    const float kval = kk[0];
    if (lane < 16) {
        const int c = (w * 16 + lane) * 4;
#pragma unroll
        for (int r = 0; r < ROWS; ++r) {
            const float4 xv4 = *(const float4*)(x + (rowbase + r) * C_ + c);
            float4 ov;
            ov.x = kval * (acc[r][0] * rinv[r]) + xv4.x;
            ov.y = kval * (acc[r][1] * rinv[r]) + xv4.y;
            ov.z = kval * (acc[r][2] * rinv[r]) + xv4.z;
            ov.w = kval * (acc[r][3] * rinv[r]) + xv4.w;
            *(float4*)(out + (rowbase + r) * (2 * C_) + c) = ov;
        }
    }
}

extern "C" void kernel_launch(void* const* d_in, const int* in_sizes, int n_in,
                              void* d_out, int out_size, void* d_ws, size_t ws_size,
                              hipStream_t stream) {
    const float* g  = (const float*)d_in[0];
    const float* x  = (const float*)d_in[1];
    const float* xq = (const float*)d_in[2];
    const float* pg = (const float*)d_in[3];
    const float* xv = (const float*)d_in[4];
    const float* kk = (const float*)d_in[5];
    float* out = (float*)d_out;

    const int B = in_sizes[0] / (N_ * C_);   // 4
    const size_t qn = (size_t)B * N_ * D_;
    const size_t vn = (size_t)B * N_ * C_;
    const size_t need = (2 * qn + vn) * sizeof(unsigned short);

    if (ws_size < need) {
        attn_fallback<<<dim3(B * (N_ / ROWS)), FNT, 0, stream>>>(g, x, xq, pg, xv, kk, out);
        return;
    }

    unsigned short* qbf  = (unsigned short*)d_ws;
    unsigned short* pgbf = qbf + qn;
    unsigned short* vt2  = pgbf + qn;

    prepass_kernel<<<dim3(512 + B * 512), 256, 0, stream>>>(xq, pg, xv, qbf, pgbf, vt2);
    attn_main<<<dim3(B * (N_ / 64)), 512, 0, stream>>>(g, x, kk, out, qbf, pgbf, vt2);
}